// Round 3
// baseline (520.313 us; speedup 1.0000x reference)
//
#include <hip/hip_runtime.h>
#include <hip/hip_bf16.h>

#define B_  2
#define D_  256
#define H_  8
#define T_  128
#define S_  128
#define F_  64
#define C_  512
#define TE_ 512

typedef _Float16 f16x8 __attribute__((ext_vector_type(8)));
typedef _Float16 f16x4 __attribute__((ext_vector_type(4)));
typedef float    f32x4 __attribute__((ext_vector_type(4)));

#define AS1 __attribute__((address_space(1)))
#define AS3 __attribute__((address_space(3)))

// ---------------------------------------------------------------------------
// K1: tp[row][c] = temb[row,:] @ w_time[:,c] + b_time[c] + b_dist[c]
// ---------------------------------------------------------------------------
__global__ __launch_bounds__(128) void k_time_proj(
    const float* __restrict__ temb, const float* __restrict__ w_time,
    const float* __restrict__ b_time, const float* __restrict__ b_dist,
    float* __restrict__ tp)
{
    int row = blockIdx.x;            // b*T + t
    int tid = threadIdx.x;
    __shared__ float te[TE_];
    for (int i = tid; i < TE_; i += 128)
        te[i] = temb[(size_t)row * TE_ + i];
    __syncthreads();
    int c0 = tid * 4;
    float4 b0 = *(const float4*)&b_time[c0];
    float4 b1 = *(const float4*)&b_dist[c0];
    float ax0 = 0.f, ay0 = 0.f, az0 = 0.f, aw0 = 0.f;
    float ax1 = 0.f, ay1 = 0.f, az1 = 0.f, aw1 = 0.f;
#pragma unroll 4
    for (int e = 0; e < TE_; e += 2) {
        float s0 = te[e], s1 = te[e + 1];
        float4 w0 = *(const float4*)&w_time[(size_t)e * C_ + c0];
        float4 w1 = *(const float4*)&w_time[(size_t)(e + 1) * C_ + c0];
        ax0 += s0 * w0.x; ay0 += s0 * w0.y; az0 += s0 * w0.z; aw0 += s0 * w0.w;
        ax1 += s1 * w1.x; ay1 += s1 * w1.y; az1 += s1 * w1.z; aw1 += s1 * w1.w;
    }
    float4 r;
    r.x = b0.x + b1.x + ax0 + ax1;
    r.y = b0.y + b1.y + ay0 + ay1;
    r.z = b0.z + b1.z + az0 + az1;
    r.w = b0.w + b1.w + aw0 + aw1;
    *(float4*)&tp[(size_t)row * C_ + c0] = r;
}

// ---------------------------------------------------------------------------
// K2: A[row][c] = f16( silu( tp[bt][c] + f0*wd0[c] + f1*wd1[c] + f2*wd2[c] ) )
// ---------------------------------------------------------------------------
__global__ __launch_bounds__(128) void k_embed_silu(
    const float* __restrict__ tp, const int* __restrict__ pd,
    const float* __restrict__ w_dist, _Float16* __restrict__ A)
{
    int row = blockIdx.x;
    int bt  = row >> 7;            // row / S_
    int d   = pd[row];
    float f0 = log1pf(fmaxf((float)d, 0.f));
    float f1 = log1pf(fmaxf((float)(-d), 0.f));
    float f2 = (d == 0) ? 1.f : 0.f;
    int c0 = threadIdx.x * 4;
    float4 t4 = *(const float4*)&tp[(size_t)bt * C_ + c0];
    float4 w0 = *(const float4*)&w_dist[c0];
    float4 w1 = *(const float4*)&w_dist[C_ + c0];
    float4 w2 = *(const float4*)&w_dist[2 * C_ + c0];
    float e0 = t4.x + f0 * w0.x + f1 * w1.x + f2 * w2.x;
    float e1 = t4.y + f0 * w0.y + f1 * w1.y + f2 * w2.y;
    float e2 = t4.z + f0 * w0.z + f1 * w1.z + f2 * w2.z;
    float e3 = t4.w + f0 * w0.w + f1 * w1.w + f2 * w2.w;
    f16x4 v;
    v[0] = (_Float16)(e0 / (1.f + expf(-e0)));
    v[1] = (_Float16)(e1 / (1.f + expf(-e1)));
    v[2] = (_Float16)(e2 / (1.f + expf(-e2)));
    v[3] = (_Float16)(e3 / (1.f + expf(-e3)));
    *(f16x4*)&A[(size_t)row * C_ + c0] = v;
}

// ---------------------------------------------------------------------------
// K2b: Wt[n][k] = f16(w_out[k][n])   (512 x 512)
// ---------------------------------------------------------------------------
__global__ __launch_bounds__(512) void k_wt(
    const float* __restrict__ w_out, _Float16* __restrict__ Wt)
{
    int n = blockIdx.x;
    int k = threadIdx.x;
    Wt[(size_t)n * C_ + k] = (_Float16)w_out[(size_t)k * C_ + n];
}

// ---------------------------------------------------------------------------
// KF: fused R-GEMM + einsum. One block per (b, t, hgroup of 4 heads).
// Phase 1 (m97 structure): Rs[s][c] = A[bt*128+s,:] @ Wt[hg*256+c,:]^T + b_out
//          -> f16 in LDS, never touches HBM (saves 96 MB R round-trip).
//          Operand-swapped MFMA puts c on the register axis -> f16x4 ds_write.
//          Rs XOR swizzle (byte ^= (s&1)<<6): GEMM2 frag reads touch 16 rows x
//          64B; alternating rows between bank halves balances all 32 banks.
// Phase 2 (= round-1 k_einsum, passed): out[d, s] per head from qk (global,
//          fp32->f16 in-reg) x Rs (LDS), f32x4 stores (s on register axis).
// ---------------------------------------------------------------------------
__global__ __launch_bounds__(512) void k_fused(
    const float* __restrict__ qk, const _Float16* __restrict__ A,
    const _Float16* __restrict__ Wt, const float* __restrict__ b_out,
    float* __restrict__ out)
{
    __shared__ alignas(16) _Float16 Rs[128][256];   // 64 KB
    __shared__ alignas(16) _Float16 As[128][64];    // 16 KB
    __shared__ alignas(16) _Float16 Wts[256][64];   // 32 KB

    int bt = blockIdx.x >> 1;
    int hg = blockIdx.x & 1;
    int b  = bt >> 7, t = bt & 127;
    int tid  = threadIdx.x;
    int wave = tid >> 6, lane = tid & 63;
    int mrow = lane & 15, kq = (lane >> 4) * 8;
    int grow = lane >> 3, gcol = (lane & 7) * 8;

    // ---------------- Phase 1: Rs = silu-A @ Wt^T + b_out ----------------
    int wm1 = (wave & 1) * 64;      // s  (2 x 64 = 128)
    int wn1 = (wave >> 1) * 64;     // c  (4 x 64 = 256)
    const size_t arow0 = (size_t)bt * 128;
    f32x4 acc[4][4] = {};           // [j: c-tile][i: s-tile]
    for (int k0 = 0; k0 < 512; k0 += 64) {
#pragma unroll
        for (int q = 0; q < 2; ++q) {
            int ch = wave * 2 + q;                       // 16 chunks x 8 rows
            __builtin_amdgcn_global_load_lds(
                (const AS1 void*)(const void*)&A[(arow0 + ch * 8 + grow) * 512 + k0 + gcol],
                (AS3 void*)(void*)&As[ch * 8][0], 16, 0, 0);
        }
#pragma unroll
        for (int q = 0; q < 4; ++q) {
            int ch = wave * 4 + q;                       // 32 chunks x 8 rows
            __builtin_amdgcn_global_load_lds(
                (const AS1 void*)(const void*)&Wt[(size_t)(hg * 256 + ch * 8 + grow) * 512 + k0 + gcol],
                (AS3 void*)(void*)&Wts[ch * 8][0], 16, 0, 0);
        }
        __syncthreads();
#pragma unroll
        for (int ks = 0; ks < 64; ks += 32) {
            f16x8 af[4], wtf[4];
#pragma unroll
            for (int i = 0; i < 4; ++i) af[i]  = *(const f16x8*)&As[wm1 + i * 16 + mrow][ks + kq];
#pragma unroll
            for (int j = 0; j < 4; ++j) wtf[j] = *(const f16x8*)&Wts[wn1 + j * 16 + mrow][ks + kq];
#pragma unroll
            for (int j = 0; j < 4; ++j)
#pragma unroll
                for (int i = 0; i < 4; ++i)
                    acc[j][i] = __builtin_amdgcn_mfma_f32_16x16x32_f16(wtf[j], af[i], acc[j][i], 0, 0, 0);
        }
        __syncthreads();
    }
    // epilogue: reg axis = c (4 consecutive), lane&15 = s
    char* rsb = (char*)&Rs[0][0];
    {
        int cg = (lane >> 4) * 4;
#pragma unroll
        for (int j = 0; j < 4; ++j) {
            int c = wn1 + j * 16 + cg;
            float4 bo = *(const float4*)&b_out[hg * 256 + c];
#pragma unroll
            for (int i = 0; i < 4; ++i) {
                int s = wm1 + i * 16 + mrow;
                f16x4 hv;
                hv[0] = (_Float16)(acc[j][i][0] + bo.x);
                hv[1] = (_Float16)(acc[j][i][1] + bo.y);
                hv[2] = (_Float16)(acc[j][i][2] + bo.z);
                hv[3] = (_Float16)(acc[j][i][3] + bo.w);
                *(f16x4*)(rsb + ((((s << 8) + c) << 1) ^ ((s & 1) << 6))) = hv;
            }
        }
    }
    __syncthreads();

    // ---------------- Phase 2: out = qk . Rs ----------------
    int wm2 = (wave >> 1) * 64;     // d  (4 x 64 = 256)
    int wn2 = (wave & 1) * 64;      // s  (2 x 64 = 128)
    const size_t qstr = (size_t)(H_ * T_ * F_);
    const size_t ostr = (size_t)(H_ * T_ * S_);
    int dcol = lane & 15, sb = (lane >> 4) * 4;
    for (int hp = 0; hp < 4; ++hp) {
        int h = hg * 4 + hp;
        const size_t qbase = (size_t)b * (D_ * H_ * T_ * F_) + (size_t)h * (T_ * F_)
                           + (size_t)t * F_;
        f32x4 acc2[4][4] = {};      // [j: s-tile][i: d-tile]
#pragma unroll
        for (int ks = 0; ks < 64; ks += 32) {
            f16x8 rf[4], qf[4];
#pragma unroll
            for (int j = 0; j < 4; ++j) {
                int s = wn2 + j * 16 + mrow;
                rf[j] = *(const f16x8*)(rsb + ((((s << 8) + hp * 64 + ks + kq) << 1) ^ ((s & 1) << 6)));
            }
#pragma unroll
            for (int i = 0; i < 4; ++i) {
                const float* qp = &qk[qbase + (size_t)(wm2 + i * 16 + mrow) * qstr + ks + kq];
                float4 u = *(const float4*)qp;
                float4 v = *(const float4*)(qp + 4);
                f16x8 a;
                a[0] = (_Float16)u.x; a[1] = (_Float16)u.y;
                a[2] = (_Float16)u.z; a[3] = (_Float16)u.w;
                a[4] = (_Float16)v.x; a[5] = (_Float16)v.y;
                a[6] = (_Float16)v.z; a[7] = (_Float16)v.w;
                qf[i] = a;
            }
#pragma unroll
            for (int j = 0; j < 4; ++j)
#pragma unroll
                for (int i = 0; i < 4; ++i)
                    acc2[j][i] = __builtin_amdgcn_mfma_f32_16x16x32_f16(rf[j], qf[i], acc2[j][i], 0, 0, 0);
        }
        const size_t obase = (size_t)b * (D_ * H_ * T_ * S_) + (size_t)h * (T_ * S_)
                           + (size_t)t * S_;
#pragma unroll
        for (int i = 0; i < 4; ++i) {
            size_t orow = obase + (size_t)(wm2 + i * 16 + dcol) * ostr;
#pragma unroll
            for (int j = 0; j < 4; ++j)
                *(f32x4*)&out[orow + wn2 + j * 16 + sb] = acc2[j][i];
        }
    }
}

// ---------------------------------------------------------------------------
extern "C" void kernel_launch(void* const* d_in, const int* in_sizes, int n_in,
                              void* d_out, int out_size, void* d_ws, size_t ws_size,
                              hipStream_t stream) {
    (void)in_sizes; (void)n_in; (void)out_size; (void)ws_size;
    const float* qk     = (const float*)d_in[0];
    const float* temb   = (const float*)d_in[1];
    const int*   pd     = (const int*)d_in[2];
    const float* w_dist = (const float*)d_in[3];
    const float* b_dist = (const float*)d_in[4];
    const float* w_time = (const float*)d_in[5];
    const float* b_time = (const float*)d_in[6];
    const float* w_out  = (const float*)d_in[7];
    const float* b_out  = (const float*)d_in[8];
    float* out = (float*)d_out;

    char* ws = (char*)d_ws;
    float*     tp = (float*)ws;                                  // 512 KB
    _Float16*  Wt = (_Float16*)(ws + 512 * 1024);                // 512 KB
    _Float16*  A  = (_Float16*)(ws + 1024 * 1024);               // 32 MB

    k_time_proj<<<dim3(B_ * T_), dim3(128), 0, stream>>>(temb, w_time, b_time, b_dist, tp);
    k_wt<<<dim3(C_), dim3(C_), 0, stream>>>(w_out, Wt);
    k_embed_silu<<<dim3(B_ * T_ * S_), dim3(128), 0, stream>>>(tp, pd, w_dist, A);
    k_fused<<<dim3(B_ * T_ * 2), dim3(512), 0, stream>>>(qk, A, Wt, b_out, out);
}

// Round 4
// 500.376 us; speedup vs baseline: 1.0398x; 1.0398x over previous
//
#include <hip/hip_runtime.h>
#include <hip/hip_bf16.h>

#define B_  2
#define D_  256
#define H_  8
#define T_  128
#define S_  128
#define F_  64
#define C_  512
#define TE_ 512

typedef _Float16 f16x8 __attribute__((ext_vector_type(8)));
typedef _Float16 f16x4 __attribute__((ext_vector_type(4)));
typedef float    f32x4 __attribute__((ext_vector_type(4)));

#define AS1 __attribute__((address_space(1)))
#define AS3 __attribute__((address_space(3)))

// ---------------------------------------------------------------------------
// K1: tp[row][c] = temb[row,:] @ w_time[:,c] + b_time[c] + b_dist[c]
// ---------------------------------------------------------------------------
__global__ __launch_bounds__(128) void k_time_proj(
    const float* __restrict__ temb, const float* __restrict__ w_time,
    const float* __restrict__ b_time, const float* __restrict__ b_dist,
    float* __restrict__ tp)
{
    int row = blockIdx.x;            // b*T + t
    int tid = threadIdx.x;
    __shared__ float te[TE_];
    for (int i = tid; i < TE_; i += 128)
        te[i] = temb[(size_t)row * TE_ + i];
    __syncthreads();
    int c0 = tid * 4;
    float4 b0 = *(const float4*)&b_time[c0];
    float4 b1 = *(const float4*)&b_dist[c0];
    float ax0 = 0.f, ay0 = 0.f, az0 = 0.f, aw0 = 0.f;
    float ax1 = 0.f, ay1 = 0.f, az1 = 0.f, aw1 = 0.f;
#pragma unroll 4
    for (int e = 0; e < TE_; e += 2) {
        float s0 = te[e], s1 = te[e + 1];
        float4 w0 = *(const float4*)&w_time[(size_t)e * C_ + c0];
        float4 w1 = *(const float4*)&w_time[(size_t)(e + 1) * C_ + c0];
        ax0 += s0 * w0.x; ay0 += s0 * w0.y; az0 += s0 * w0.z; aw0 += s0 * w0.w;
        ax1 += s1 * w1.x; ay1 += s1 * w1.y; az1 += s1 * w1.z; aw1 += s1 * w1.w;
    }
    float4 r;
    r.x = b0.x + b1.x + ax0 + ax1;
    r.y = b0.y + b1.y + ay0 + ay1;
    r.z = b0.z + b1.z + az0 + az1;
    r.w = b0.w + b1.w + aw0 + aw1;
    *(float4*)&tp[(size_t)row * C_ + c0] = r;
}

// ---------------------------------------------------------------------------
// K2: A[row][c] = f16( silu( tp[bt][c] + f0*wd0[c] + f1*wd1[c] + f2*wd2[c] ) )
// ---------------------------------------------------------------------------
__global__ __launch_bounds__(128) void k_embed_silu(
    const float* __restrict__ tp, const int* __restrict__ pd,
    const float* __restrict__ w_dist, _Float16* __restrict__ A)
{
    int row = blockIdx.x;
    int bt  = row >> 7;            // row / S_
    int d   = pd[row];
    float f0 = log1pf(fmaxf((float)d, 0.f));
    float f1 = log1pf(fmaxf((float)(-d), 0.f));
    float f2 = (d == 0) ? 1.f : 0.f;
    int c0 = threadIdx.x * 4;
    float4 t4 = *(const float4*)&tp[(size_t)bt * C_ + c0];
    float4 w0 = *(const float4*)&w_dist[c0];
    float4 w1 = *(const float4*)&w_dist[C_ + c0];
    float4 w2 = *(const float4*)&w_dist[2 * C_ + c0];
    float e0 = t4.x + f0 * w0.x + f1 * w1.x + f2 * w2.x;
    float e1 = t4.y + f0 * w0.y + f1 * w1.y + f2 * w2.y;
    float e2 = t4.z + f0 * w0.z + f1 * w1.z + f2 * w2.z;
    float e3 = t4.w + f0 * w0.w + f1 * w1.w + f2 * w2.w;
    f16x4 v;
    v[0] = (_Float16)(e0 / (1.f + expf(-e0)));
    v[1] = (_Float16)(e1 / (1.f + expf(-e1)));
    v[2] = (_Float16)(e2 / (1.f + expf(-e2)));
    v[3] = (_Float16)(e3 / (1.f + expf(-e3)));
    *(f16x4*)&A[(size_t)row * C_ + c0] = v;
}

// ---------------------------------------------------------------------------
// K2b: Wt[n][k] = f16(w_out[k][n])   (512 x 512)
// ---------------------------------------------------------------------------
__global__ __launch_bounds__(512) void k_wt(
    const float* __restrict__ w_out, _Float16* __restrict__ Wt)
{
    int n = blockIdx.x;
    int k = threadIdx.x;
    Wt[(size_t)n * C_ + k] = (_Float16)w_out[(size_t)k * C_ + n];
}

// ---------------------------------------------------------------------------
// KF: fused R-GEMM + einsum. One block per (b, t, hgroup of 4 heads).
// Round-3 fixes (latency-bound: 17% occ, 9.7M bank conflicts):
//  * LDS union: {As 16K + Wts 32K} (K-loop) aliased with Rs 64K (post-loop)
//    -> 64 KB total -> 2 blocks/CU, all 512 blocks resident.
//  * G4 XOR swizzles (m201 recipe, rule #21): As/Wts staged via
//    inverse-swizzled GLOBAL source (seg ^= row&7), linear gll dest,
//    swizzled ds_read (byte ^= (row&7)<<4). Rs ds_write/ds_read both
//    swizzled byte ^= (s&7)<<4. Consecutive lanes -> 8 distinct 16B quads.
// ---------------------------------------------------------------------------
__global__ __launch_bounds__(512, 4) void k_fused(
    const float* __restrict__ qk, const _Float16* __restrict__ A,
    const _Float16* __restrict__ Wt, const float* __restrict__ b_out,
    float* __restrict__ out)
{
    // union: phase1 { As[128][64] @0 (16KB), Wts[256][64] @16384 (32KB) }
    //        phase2   Rs[128][256] @0 (64KB, f16, swizzled)
    __shared__ alignas(16) char smem[65536];
    char* asb = smem;
    char* wtb = smem + 16384;
    char* rsb = smem;

    int bt = blockIdx.x >> 1;
    int hg = blockIdx.x & 1;
    int b  = bt >> 7, t = bt & 127;
    int tid  = threadIdx.x;
    int wave = tid >> 6, lane = tid & 63;
    int mrow = lane & 15, kq = (lane >> 4) * 8;
    int swz  = (mrow & 7) << 4;          // per-lane read/write XOR (bits 4-6)
    // gll staging: lane l fills LDS chunkbase + l*16 (linear). Source column
    // segment is inverse-swizzled so LDS[row][seg] = G[row][seg ^ (row&7)].
    int grow = lane >> 3;                // row within 8-row chunk (== row&7)
    int gcol = ((lane & 7) ^ grow) * 8;  // f16 units, involution

    // ---------------- Phase 1: Rs = silu-A @ Wt^T + b_out ----------------
    int wm1 = (wave & 1) * 64;      // s  (2 x 64 = 128)
    int wn1 = (wave >> 1) * 64;     // c  (4 x 64 = 256)
    const size_t arow0 = (size_t)bt * 128;
    f32x4 acc[4][4] = {};           // [j: c-tile][i: s-tile]
    for (int k0 = 0; k0 < 512; k0 += 64) {
#pragma unroll
        for (int q = 0; q < 2; ++q) {
            int ch = wave * 2 + q;                       // 16 chunks x 8 rows
            __builtin_amdgcn_global_load_lds(
                (const AS1 void*)(const void*)&A[(arow0 + ch * 8 + grow) * 512 + k0 + gcol],
                (AS3 void*)(void*)(asb + ch * 1024), 16, 0, 0);
        }
#pragma unroll
        for (int q = 0; q < 4; ++q) {
            int ch = wave * 4 + q;                       // 32 chunks x 8 rows
            __builtin_amdgcn_global_load_lds(
                (const AS1 void*)(const void*)&Wt[(size_t)(hg * 256 + ch * 8 + grow) * 512 + k0 + gcol],
                (AS3 void*)(void*)(wtb + ch * 1024), 16, 0, 0);
        }
        __syncthreads();
#pragma unroll
        for (int ks = 0; ks < 64; ks += 32) {
            f16x8 af[4], wtf[4];
#pragma unroll
            for (int i = 0; i < 4; ++i) {
                int row = wm1 + i * 16 + mrow;           // row&7 == mrow&7
                af[i] = *(const f16x8*)(asb + (((row << 7) + ((ks + kq) << 1)) ^ swz));
            }
#pragma unroll
            for (int j = 0; j < 4; ++j) {
                int row = wn1 + j * 16 + mrow;
                wtf[j] = *(const f16x8*)(wtb + (((row << 7) + ((ks + kq) << 1)) ^ swz));
            }
#pragma unroll
            for (int j = 0; j < 4; ++j)
#pragma unroll
                for (int i = 0; i < 4; ++i)
                    acc[j][i] = __builtin_amdgcn_mfma_f32_16x16x32_f16(wtf[j], af[i], acc[j][i], 0, 0, 0);
        }
        __syncthreads();
    }
    // epilogue: reg axis = c (4 consecutive), lane&15 = s.  Rs aliases As/Wts
    // (both dead after the loop-end barrier above).
    {
        int cg = (lane >> 4) * 4;
#pragma unroll
        for (int j = 0; j < 4; ++j) {
            int c = wn1 + j * 16 + cg;
            float4 bo = *(const float4*)&b_out[hg * 256 + c];
#pragma unroll
            for (int i = 0; i < 4; ++i) {
                int s = wm1 + i * 16 + mrow;             // s&7 == mrow&7
                f16x4 hv;
                hv[0] = (_Float16)(acc[j][i][0] + bo.x);
                hv[1] = (_Float16)(acc[j][i][1] + bo.y);
                hv[2] = (_Float16)(acc[j][i][2] + bo.z);
                hv[3] = (_Float16)(acc[j][i][3] + bo.w);
                *(f16x4*)(rsb + (((s << 9) + (c << 1)) ^ swz)) = hv;
            }
        }
    }
    __syncthreads();

    // ---------------- Phase 2: out = qk . Rs ----------------
    int wm2 = (wave >> 1) * 64;     // d  (4 x 64 = 256)
    int wn2 = (wave & 1) * 64;      // s  (2 x 64 = 128)
    const size_t qstr = (size_t)(H_ * T_ * F_);
    const size_t ostr = (size_t)(H_ * T_ * S_);
    int dcol = lane & 15, sb = (lane >> 4) * 4;
    for (int hp = 0; hp < 4; ++hp) {
        int h = hg * 4 + hp;
        const size_t qbase = (size_t)b * (D_ * H_ * T_ * F_) + (size_t)h * (T_ * F_)
                           + (size_t)t * F_;
        f32x4 acc2[4][4] = {};      // [j: s-tile][i: d-tile]
#pragma unroll
        for (int ks = 0; ks < 64; ks += 32) {
            f16x8 rf[4], qf[4];
#pragma unroll
            for (int j = 0; j < 4; ++j) {
                int s = wn2 + j * 16 + mrow;             // s&7 == mrow&7
                rf[j] = *(const f16x8*)(rsb + (((s << 9) + ((hp * 64 + ks + kq) << 1)) ^ swz));
            }
#pragma unroll
            for (int i = 0; i < 4; ++i) {
                const float* qp = &qk[qbase + (size_t)(wm2 + i * 16 + mrow) * qstr + ks + kq];
                float4 u = *(const float4*)qp;
                float4 v = *(const float4*)(qp + 4);
                f16x8 a;
                a[0] = (_Float16)u.x; a[1] = (_Float16)u.y;
                a[2] = (_Float16)u.z; a[3] = (_Float16)u.w;
                a[4] = (_Float16)v.x; a[5] = (_Float16)v.y;
                a[6] = (_Float16)v.z; a[7] = (_Float16)v.w;
                qf[i] = a;
            }
#pragma unroll
            for (int j = 0; j < 4; ++j)
#pragma unroll
                for (int i = 0; i < 4; ++i)
                    acc2[j][i] = __builtin_amdgcn_mfma_f32_16x16x32_f16(rf[j], qf[i], acc2[j][i], 0, 0, 0);
        }
        const size_t obase = (size_t)b * (D_ * H_ * T_ * S_) + (size_t)h * (T_ * S_)
                           + (size_t)t * S_;
#pragma unroll
        for (int i = 0; i < 4; ++i) {
            size_t orow = obase + (size_t)(wm2 + i * 16 + dcol) * ostr;
#pragma unroll
            for (int j = 0; j < 4; ++j)
                *(f32x4*)&out[orow + wn2 + j * 16 + sb] = acc2[j][i];
        }
    }
}

// ---------------------------------------------------------------------------
extern "C" void kernel_launch(void* const* d_in, const int* in_sizes, int n_in,
                              void* d_out, int out_size, void* d_ws, size_t ws_size,
                              hipStream_t stream) {
    (void)in_sizes; (void)n_in; (void)out_size; (void)ws_size;
    const float* qk     = (const float*)d_in[0];
    const float* temb   = (const float*)d_in[1];
    const int*   pd     = (const int*)d_in[2];
    const float* w_dist = (const float*)d_in[3];
    const float* b_dist = (const float*)d_in[4];
    const float* w_time = (const float*)d_in[5];
    const float* b_time = (const float*)d_in[6];
    const float* w_out  = (const float*)d_in[7];
    const float* b_out  = (const float*)d_in[8];
    float* out = (float*)d_out;

    char* ws = (char*)d_ws;
    float*     tp = (float*)ws;                                  // 512 KB
    _Float16*  Wt = (_Float16*)(ws + 512 * 1024);                // 512 KB
    _Float16*  A  = (_Float16*)(ws + 1024 * 1024);               // 32 MB

    k_time_proj<<<dim3(B_ * T_), dim3(128), 0, stream>>>(temb, w_time, b_time, b_dist, tp);
    k_wt<<<dim3(C_), dim3(C_), 0, stream>>>(w_out, Wt);
    k_embed_silu<<<dim3(B_ * T_ * S_), dim3(128), 0, stream>>>(tp, pd, w_dist, A);
    k_fused<<<dim3(B_ * T_ * 2), dim3(512), 0, stream>>>(qk, A, Wt, b_out, out);
}

// Round 5
// 478.545 us; speedup vs baseline: 1.0873x; 1.0456x over previous
//
#include <hip/hip_runtime.h>
#include <hip/hip_bf16.h>

#define B_  2
#define D_  256
#define H_  8
#define T_  128
#define S_  128
#define F_  64
#define C_  512
#define TE_ 512

typedef _Float16 f16x8 __attribute__((ext_vector_type(8)));
typedef _Float16 f16x4 __attribute__((ext_vector_type(4)));
typedef float    f32x4 __attribute__((ext_vector_type(4)));

#define AS1 __attribute__((address_space(1)))
#define AS3 __attribute__((address_space(3)))

// ---------------------------------------------------------------------------
// K1: tp[row][c] = temb[row,:] @ w_time[:,c] + b_time[c] + b_dist[c]
// ---------------------------------------------------------------------------
__global__ __launch_bounds__(128) void k_time_proj(
    const float* __restrict__ temb, const float* __restrict__ w_time,
    const float* __restrict__ b_time, const float* __restrict__ b_dist,
    float* __restrict__ tp)
{
    int row = blockIdx.x;            // b*T + t
    int tid = threadIdx.x;
    __shared__ float te[TE_];
    for (int i = tid; i < TE_; i += 128)
        te[i] = temb[(size_t)row * TE_ + i];
    __syncthreads();
    int c0 = tid * 4;
    float4 b0 = *(const float4*)&b_time[c0];
    float4 b1 = *(const float4*)&b_dist[c0];
    float ax0 = 0.f, ay0 = 0.f, az0 = 0.f, aw0 = 0.f;
    float ax1 = 0.f, ay1 = 0.f, az1 = 0.f, aw1 = 0.f;
#pragma unroll 4
    for (int e = 0; e < TE_; e += 2) {
        float s0 = te[e], s1 = te[e + 1];
        float4 w0 = *(const float4*)&w_time[(size_t)e * C_ + c0];
        float4 w1 = *(const float4*)&w_time[(size_t)(e + 1) * C_ + c0];
        ax0 += s0 * w0.x; ay0 += s0 * w0.y; az0 += s0 * w0.z; aw0 += s0 * w0.w;
        ax1 += s1 * w1.x; ay1 += s1 * w1.y; az1 += s1 * w1.z; aw1 += s1 * w1.w;
    }
    float4 r;
    r.x = b0.x + b1.x + ax0 + ax1;
    r.y = b0.y + b1.y + ay0 + ay1;
    r.z = b0.z + b1.z + az0 + az1;
    r.w = b0.w + b1.w + aw0 + aw1;
    *(float4*)&tp[(size_t)row * C_ + c0] = r;
}

// ---------------------------------------------------------------------------
// K2b: Wt[n][k] = f16(w_out[k][n])   (512 x 512)
// ---------------------------------------------------------------------------
__global__ __launch_bounds__(512) void k_wt(
    const float* __restrict__ w_out, _Float16* __restrict__ Wt)
{
    int n = blockIdx.x;
    int k = threadIdx.x;
    Wt[(size_t)n * C_ + k] = (_Float16)w_out[(size_t)k * C_ + n];
}

// ---------------------------------------------------------------------------
// KF: fused embed-silu + R-GEMM + einsum. One block per (b, t, hgroup of 4).
// Round-4 change: A is never materialized in HBM. Phase 1 computes the
// silu(A) tile in-register per K-tile (tp row + w_dist staged in LDS, pd
// per row) and ds_writes it at the SAME swizzled addresses the fragment
// reads use (write/read share one involution, rule #21). Kills the K2
// dispatch, the 33.5 MB A write, and the 67 MB A re-read. VALU was 4.8%
// busy -> recompute hides under MFMA/load latency. Wts gll issued first
// so its latency hides under the As compute.
// ---------------------------------------------------------------------------
__global__ __launch_bounds__(512, 4) void k_fused(
    const float* __restrict__ qk, const float* __restrict__ tp,
    const int* __restrict__ pd, const float* __restrict__ w_dist,
    const _Float16* __restrict__ Wt, const float* __restrict__ b_out,
    float* __restrict__ out)
{
    // union: phase1 { As 16KB @0, Wts 32KB @16384, tp/w_dist 8KB @49152 }
    //        phase2   Rs[128][256] 64KB @0 (f16, swizzled)
    __shared__ alignas(16) char smem[65536];
    char*  asb = smem;
    char*  wtb = smem + 16384;
    float* tpw = (float*)(smem + 49152);
    char*  rsb = smem;

    int bt = blockIdx.x >> 1;
    int hg = blockIdx.x & 1;
    int b  = bt >> 7, t = bt & 127;
    int tid  = threadIdx.x;
    int wave = tid >> 6, lane = tid & 63;
    int mrow = lane & 15, kq = (lane >> 4) * 8;
    int swz  = (mrow & 7) << 4;          // fragment-read XOR (bits 4-6)
    // Wts gll staging: linear LDS dest, inverse-swizzled global source col.
    int grow = lane >> 3;                // row within 8-row chunk (== row&7)
    int gcol = ((lane & 7) ^ grow) * 8;  // f16 units, involution

    // stage tp row (512 f32) + w_dist (3x512 f32) into LDS: 4 f32/thread
    tpw[tid]        = tp[(size_t)bt * 512 + tid];
    tpw[512 + tid]  = w_dist[tid];
    tpw[1024 + tid] = w_dist[512 + tid];
    tpw[1536 + tid] = w_dist[1024 + tid];

    // per-thread A-generator constants: row s = tid>>2, 16 cols per K-tile
    int as_s  = tid >> 2;                // 0..127
    int as_cb = (tid & 3) * 16;          // col base (f16 idx) in 64-wide tile
    int as_swz = (as_s & 7) << 4;
    int dpd = pd[bt * 128 + as_s];
    float f0 = log1pf(fmaxf((float)dpd, 0.f));
    float f1 = log1pf(fmaxf((float)(-dpd), 0.f));
    float f2 = (dpd == 0) ? 1.f : 0.f;
    __syncthreads();                     // tpw ready

    const float* tpL = tpw;
    const float* w0L = tpw + 512;
    const float* w1L = tpw + 1024;
    const float* w2L = tpw + 1536;

    // ---------------- Phase 1: Rs = silu-A @ Wt^T + b_out ----------------
    int wm1 = (wave & 1) * 64;      // s  (2 x 64 = 128)
    int wn1 = (wave >> 1) * 64;     // c  (4 x 64 = 256)
    f32x4 acc[4][4] = {};           // [j: c-tile][i: s-tile]
    for (int k0 = 0; k0 < 512; k0 += 64) {
        // issue Wts staging first: HBM/L2 latency hides under As compute
#pragma unroll
        for (int q = 0; q < 4; ++q) {
            int ch = wave * 4 + q;                       // 32 chunks x 8 rows
            __builtin_amdgcn_global_load_lds(
                (const AS1 void*)(const void*)&Wt[(size_t)(hg * 256 + ch * 8 + grow) * 512 + k0 + gcol],
                (AS3 void*)(void*)(wtb + ch * 1024), 16, 0, 0);
        }
        // compute As[as_s][k0+as_cb .. +15] = silu(tp + f.w_dist)
        float ev[16];
#pragma unroll
        for (int u4 = 0; u4 < 4; ++u4) {
            int k = k0 + as_cb + u4 * 4;
            float4 tv = *(const float4*)&tpL[k];
            float4 a0 = *(const float4*)&w0L[k];
            float4 a1 = *(const float4*)&w1L[k];
            float4 a2 = *(const float4*)&w2L[k];
            ev[u4 * 4 + 0] = tv.x + f0 * a0.x + f1 * a1.x + f2 * a2.x;
            ev[u4 * 4 + 1] = tv.y + f0 * a0.y + f1 * a1.y + f2 * a2.y;
            ev[u4 * 4 + 2] = tv.z + f0 * a0.z + f1 * a1.z + f2 * a2.z;
            ev[u4 * 4 + 3] = tv.w + f0 * a0.w + f1 * a1.w + f2 * a2.w;
        }
        f16x8 h0, h1;
#pragma unroll
        for (int u = 0; u < 8; ++u) {
            float e0 = ev[u], e1 = ev[8 + u];
            h0[u] = (_Float16)(e0 / (1.f + expf(-e0)));
            h1[u] = (_Float16)(e1 / (1.f + expf(-e1)));
        }
        int cb2 = as_cb * 2;             // byte offset in 128-B row
        *(f16x8*)(asb + (((as_s << 7) + cb2)      ^ as_swz)) = h0;
        *(f16x8*)(asb + (((as_s << 7) + cb2 + 16) ^ as_swz)) = h1;
        __syncthreads();
#pragma unroll
        for (int ks = 0; ks < 64; ks += 32) {
            f16x8 af[4], wtf[4];
#pragma unroll
            for (int i = 0; i < 4; ++i) {
                int row = wm1 + i * 16 + mrow;           // row&7 == mrow&7
                af[i] = *(const f16x8*)(asb + (((row << 7) + ((ks + kq) << 1)) ^ swz));
            }
#pragma unroll
            for (int j = 0; j < 4; ++j) {
                int row = wn1 + j * 16 + mrow;
                wtf[j] = *(const f16x8*)(wtb + (((row << 7) + ((ks + kq) << 1)) ^ swz));
            }
#pragma unroll
            for (int j = 0; j < 4; ++j)
#pragma unroll
                for (int i = 0; i < 4; ++i)
                    acc[j][i] = __builtin_amdgcn_mfma_f32_16x16x32_f16(wtf[j], af[i], acc[j][i], 0, 0, 0);
        }
        __syncthreads();
    }
    // epilogue: reg axis = c (4 consecutive), lane&15 = s.  Rs aliases the
    // phase-1 buffers (all dead after the loop-end barrier).
    {
        int cg = (lane >> 4) * 4;
#pragma unroll
        for (int j = 0; j < 4; ++j) {
            int c = wn1 + j * 16 + cg;
            float4 bo = *(const float4*)&b_out[hg * 256 + c];
#pragma unroll
            for (int i = 0; i < 4; ++i) {
                int s = wm1 + i * 16 + mrow;             // s&7 == mrow&7
                f16x4 hv;
                hv[0] = (_Float16)(acc[j][i][0] + bo.x);
                hv[1] = (_Float16)(acc[j][i][1] + bo.y);
                hv[2] = (_Float16)(acc[j][i][2] + bo.z);
                hv[3] = (_Float16)(acc[j][i][3] + bo.w);
                *(f16x4*)(rsb + (((s << 9) + (c << 1)) ^ swz)) = hv;
            }
        }
    }
    __syncthreads();

    // ---------------- Phase 2: out = qk . Rs ----------------
    int wm2 = (wave >> 1) * 64;     // d  (4 x 64 = 256)
    int wn2 = (wave & 1) * 64;      // s  (2 x 64 = 128)
    const size_t qstr = (size_t)(H_ * T_ * F_);
    const size_t ostr = (size_t)(H_ * T_ * S_);
    int dcol = lane & 15, sb = (lane >> 4) * 4;
    for (int hp = 0; hp < 4; ++hp) {
        int h = hg * 4 + hp;
        const size_t qbase = (size_t)b * (D_ * H_ * T_ * F_) + (size_t)h * (T_ * F_)
                           + (size_t)t * F_;
        f32x4 acc2[4][4] = {};      // [j: s-tile][i: d-tile]
#pragma unroll
        for (int ks = 0; ks < 64; ks += 32) {
            f16x8 rf[4], qf[4];
#pragma unroll
            for (int j = 0; j < 4; ++j) {
                int s = wn2 + j * 16 + mrow;             // s&7 == mrow&7
                rf[j] = *(const f16x8*)(rsb + (((s << 9) + ((hp * 64 + ks + kq) << 1)) ^ swz));
            }
#pragma unroll
            for (int i = 0; i < 4; ++i) {
                const float* qp = &qk[qbase + (size_t)(wm2 + i * 16 + mrow) * qstr + ks + kq];
                float4 u = *(const float4*)qp;
                float4 v = *(const float4*)(qp + 4);
                f16x8 a;
                a[0] = (_Float16)u.x; a[1] = (_Float16)u.y;
                a[2] = (_Float16)u.z; a[3] = (_Float16)u.w;
                a[4] = (_Float16)v.x; a[5] = (_Float16)v.y;
                a[6] = (_Float16)v.z; a[7] = (_Float16)v.w;
                qf[i] = a;
            }
#pragma unroll
            for (int j = 0; j < 4; ++j)
#pragma unroll
                for (int i = 0; i < 4; ++i)
                    acc2[j][i] = __builtin_amdgcn_mfma_f32_16x16x32_f16(rf[j], qf[i], acc2[j][i], 0, 0, 0);
        }
        const size_t obase = (size_t)b * (D_ * H_ * T_ * S_) + (size_t)h * (T_ * S_)
                           + (size_t)t * S_;
#pragma unroll
        for (int i = 0; i < 4; ++i) {
            size_t orow = obase + (size_t)(wm2 + i * 16 + dcol) * ostr;
#pragma unroll
            for (int j = 0; j < 4; ++j)
                *(f32x4*)&out[orow + wn2 + j * 16 + sb] = acc2[j][i];
        }
    }
}

// ---------------------------------------------------------------------------
extern "C" void kernel_launch(void* const* d_in, const int* in_sizes, int n_in,
                              void* d_out, int out_size, void* d_ws, size_t ws_size,
                              hipStream_t stream) {
    (void)in_sizes; (void)n_in; (void)out_size; (void)ws_size;
    const float* qk     = (const float*)d_in[0];
    const float* temb   = (const float*)d_in[1];
    const int*   pd     = (const int*)d_in[2];
    const float* w_dist = (const float*)d_in[3];
    const float* b_dist = (const float*)d_in[4];
    const float* w_time = (const float*)d_in[5];
    const float* b_time = (const float*)d_in[6];
    const float* w_out  = (const float*)d_in[7];
    const float* b_out  = (const float*)d_in[8];
    float* out = (float*)d_out;

    char* ws = (char*)d_ws;
    float*     tp = (float*)ws;                                  // 512 KB
    _Float16*  Wt = (_Float16*)(ws + 512 * 1024);                // 512 KB

    k_time_proj<<<dim3(B_ * T_), dim3(128), 0, stream>>>(temb, w_time, b_time, b_dist, tp);
    k_wt<<<dim3(C_), dim3(C_), 0, stream>>>(w_out, Wt);
    k_fused<<<dim3(B_ * T_ * 2), dim3(512), 0, stream>>>(qk, tp, pd, w_dist, Wt, b_out, out);
}